// Round 1
// baseline (516.316 us; speedup 1.0000x reference)
//
#include <hip/hip_runtime.h>
#include <cstdint>
#include <cstddef>

#define TLEN    50
#define BATCH   16
#define D_IN    512
#define SRC_LEN 200
#define VOCAB   20000
#define CVOCAB  20400

typedef __bf16 bf16x8 __attribute__((ext_vector_type(8)));
typedef float  f32x4  __attribute__((ext_vector_type(4)));

#define GEMM_BLOCKS 157                  // ceil(20000 / 128)
#define ZERO_BLOCKS 40                   // zero cols [20000,20400) of 800 rows
#define SCAN_BLOCKS (SRC_LEN * BATCH)    // 3200 one-hot rows
#define NTHREADS 256

// Role layout: [0,157) GEMM+softmax, [157,197) tail-zero, [197,3397) src_map scan.
// GEMM blocks run longest -> dispatched first; scan blocks co-reside (19KB LDS/block).
__global__ __launch_bounds__(NTHREADS, 2)
void fused_main(const float* __restrict__ hidden,
                const float* __restrict__ src_map,
                const float* __restrict__ W,
                const float* __restrict__ Wc,
                const float* __restrict__ bc,
                float* __restrict__ out,
                int* __restrict__ src_ids)
{
    const int bid = blockIdx.x;
    const int tid = threadIdx.x;

    if (bid < GEMM_BLOCKS) {
        // ---- GEMM (logits) + softmax-over-batch + (1-p_copy) scale + store ----
        // Per block: 128 vocab cols, loop t=0..49. B-frags (W, bf16) live in
        // registers for the whole kernel: W is read from HBM exactly once.
        // NOTE: bias b[v] is uniform over the softmax (batch) axis -> cancels.
        __shared__ __align__(16) __bf16 Alds[BATCH][D_IN + 8]; // +8 pad: 2-way-only LDS conflicts
        __shared__ float WcLds[D_IN];
        __shared__ float pcLds[BATCH];

        for (int i = tid; i < D_IN; i += NTHREADS) WcLds[i] = Wc[i];
        const float bc0 = bc[0];

        const int lane = tid & 63;
        const int wv   = tid >> 6;           // wave 0..3, 32 cols each
        const int l15  = lane & 15;
        const int q    = lane >> 4;          // quad
        const int colbase = bid * 128 + wv * 32;

        bf16x8 bfrag[2][16];
        bool act[2];
        {
            bf16x8 zf;
            #pragma unroll
            for (int j = 0; j < 8; ++j) zf[j] = (__bf16)0.0f;
            #pragma unroll
            for (int g = 0; g < 2; ++g) {
                const int vb = colbase + g * 16;
                act[g] = (vb < VOCAB);       // VOCAB % 16 == 0 -> whole group valid or not
                #pragma unroll
                for (int c = 0; c < 16; ++c) bfrag[g][c] = zf;
                if (act[g]) {
                    const float* wrow = W + (size_t)(vb + l15) * D_IN + q * 8;
                    #pragma unroll
                    for (int c = 0; c < 16; ++c) {
                        float4 f0 = *(const float4*)(wrow + c * 32);
                        float4 f1 = *(const float4*)(wrow + c * 32 + 4);
                        bf16x8 bf;
                        bf[0] = (__bf16)f0.x; bf[1] = (__bf16)f0.y;
                        bf[2] = (__bf16)f0.z; bf[3] = (__bf16)f0.w;
                        bf[4] = (__bf16)f1.x; bf[5] = (__bf16)f1.y;
                        bf[6] = (__bf16)f1.z; bf[7] = (__bf16)f1.w;
                        bfrag[g][c] = bf;
                    }
                }
            }
        }

        for (int t = 0; t < TLEN; ++t) {
            __syncthreads();   // prev iter's pcLds readers done before restage
            // stage A = hidden[t] (16x512 fp32 -> bf16 LDS); 8 float4 per thread
            #pragma unroll
            for (int i = 0; i < 8; ++i) {
                const int f = tid + i * NTHREADS;        // float4 idx 0..2047
                const int b = f >> 7;                    // 128 float4 per row
                const int k = (f & 127) * 4;
                float4 v4 = *(const float4*)(hidden + (size_t)(t * BATCH + b) * D_IN + k);
                __bf16* dst = &Alds[b][k];
                dst[0] = (__bf16)v4.x; dst[1] = (__bf16)v4.y;
                dst[2] = (__bf16)v4.z; dst[3] = (__bf16)v4.w;
            }
            __syncthreads();

            // p_copy[t][b] = sigmoid(hidden[t,b,:].Wc + bc): 16 threads per b
            {
                const int b = tid >> 4, l = tid & 15;
                float s = 0.f;
                #pragma unroll
                for (int j = 0; j < 32; ++j) {
                    const int k = l + j * 16;
                    s += (float)Alds[b][k] * WcLds[k];
                }
                #pragma unroll
                for (int o = 1; o < 16; o <<= 1) s += __shfl_xor(s, o, 16);
                if (l == 0) pcLds[b] = 1.0f / (1.0f + __expf(-(s + bc0)));
            }

            // MFMA: D[b][v], A rows = batch, B cols = vocab
            f32x4 acc0 = {0.f, 0.f, 0.f, 0.f};
            f32x4 acc1 = {0.f, 0.f, 0.f, 0.f};
            const __bf16* arow = &Alds[l15][q * 8];
            #pragma unroll
            for (int c = 0; c < 16; ++c) {
                bf16x8 af = *(const bf16x8*)(arow + c * 32);
                acc0 = __builtin_amdgcn_mfma_f32_16x16x32_bf16(af, bfrag[0][c], acc0, 0, 0, 0);
                acc1 = __builtin_amdgcn_mfma_f32_16x16x32_bf16(af, bfrag[1][c], acc1, 0, 0, 0);
            }
            __syncthreads();   // pcLds written; Alds readers done

            // softmax over batch (D rows), mask b==1 -> prob 0; scale by (1-p_copy)
            #pragma unroll
            for (int g = 0; g < 2; ++g) {
                f32x4 acc = g ? acc1 : acc0;
                float mx = -INFINITY;
                #pragma unroll
                for (int r = 0; r < 4; ++r) {
                    const int b = q * 4 + r;
                    if (b != 1) mx = fmaxf(mx, acc[r]);
                }
                mx = fmaxf(mx, __shfl_xor(mx, 16));
                mx = fmaxf(mx, __shfl_xor(mx, 32));
                float e[4], s = 0.f;
                #pragma unroll
                for (int r = 0; r < 4; ++r) {
                    const int b = q * 4 + r;
                    e[r] = (b == 1) ? 0.f : __expf(acc[r] - mx);
                    s += e[r];
                }
                s += __shfl_xor(s, 16);
                s += __shfl_xor(s, 32);
                const float inv = 1.0f / s;
                if (act[g]) {
                    const int v = colbase + g * 16 + l15;
                    #pragma unroll
                    for (int r = 0; r < 4; ++r) {
                        const int b = q * 4 + r;
                        out[(size_t)(t * BATCH + b) * CVOCAB + v] =
                            e[r] * inv * (1.0f - pcLds[b]);
                    }
                }
            }
        }
    } else if (bid < GEMM_BLOCKS + ZERO_BLOCKS) {
        // ---- zero the extended-vocab tail cols [20000,20400) of all 800 rows ----
        const int zb = bid - GEMM_BLOCKS;
        const float4 z = {0.f, 0.f, 0.f, 0.f};
        for (int i = tid; i < 2000; i += NTHREADS) {
            const int f = zb * 2000 + i;    // 0..79999 float4s, 100 per row
            const int r = f / 100;
            const int c = f % 100;
            *(float4*)(out + (size_t)r * CVOCAB + VOCAB + c * 4) = z;
        }
    } else {
        // ---- scan one one-hot src_map row (20400 fp32), emit its index ----
        const int row = bid - GEMM_BLOCKS - ZERO_BLOCKS;     // (s*16+b)
        const float4* base = (const float4*)(src_map + (size_t)row * CVOCAB);
        int found = -1;
        // 5100 float4 = 4 segments of 1275; 4 independent loads in flight/iter
        for (int i0 = tid; i0 < 1275; i0 += NTHREADS) {
            float4 x0 = base[i0];
            float4 x1 = base[i0 + 1275];
            float4 x2 = base[i0 + 2550];
            float4 x3 = base[i0 + 3825];
            #pragma unroll
            for (int seg = 0; seg < 4; ++seg) {
                float4 x = seg == 0 ? x0 : seg == 1 ? x1 : seg == 2 ? x2 : x3;
                const int e0 = (i0 + seg * 1275) * 4;
                if (x.x > 0.5f) found = e0;
                if (x.y > 0.5f) found = e0 + 1;
                if (x.z > 0.5f) found = e0 + 2;
                if (x.w > 0.5f) found = e0 + 3;
            }
        }
        if (found >= 0) src_ids[row] = found;   // exactly one finder per row
    }
}

// Scatter copy-probs: for original (t,b) with r=t*16+b, the reference's
// split/stack/transpose permutation sends copy_prob[t,b,:] to output row
// (t'=r%50, b'=r/50). atomicAdd on top of the already-stored out_prob.
__global__ __launch_bounds__(64)
void scatter_copy(const float* __restrict__ hidden,
                  const float* __restrict__ attn,
                  const float* __restrict__ Wc,
                  const float* __restrict__ bc,
                  const int* __restrict__ src_ids,
                  float* __restrict__ out)
{
    const int p = blockIdx.x;            // r = t*16+b, 0..799
    const int b = p & 15;
    const int l = threadIdx.x;

    // p_copy (recomputed; 512-dot in fp32)
    float s = 0.f;
    const float* hrow = hidden + (size_t)p * D_IN;
    #pragma unroll
    for (int j = 0; j < 8; ++j) s += hrow[l + 64 * j] * Wc[l + 64 * j];
    #pragma unroll
    for (int o = 1; o < 64; o <<= 1) s += __shfl_xor(s, o);
    const float pc = 1.0f / (1.0f + __expf(-(s + bc[0])));

    const int b2 = p / 50;
    const int t2 = p % 50;
    const size_t obase = (size_t)(t2 * BATCH + b2) * CVOCAB;
    const float* arow = attn + (size_t)p * SRC_LEN;
    for (int si = l; si < SRC_LEN; si += 64) {
        const int id = src_ids[si * BATCH + b];
        const float val = arow[si] * pc;
        if ((unsigned)id < (unsigned)CVOCAB)   // defensive vs poisoned ws
            atomicAdd(out + obase + id, val);
    }
}

extern "C" void kernel_launch(void* const* d_in, const int* in_sizes, int n_in,
                              void* d_out, int out_size, void* d_ws, size_t ws_size,
                              hipStream_t stream)
{
    const float* hidden  = (const float*)d_in[0];  // (50,16,512)
    const float* attn    = (const float*)d_in[1];  // (50,16,200)
    const float* src_map = (const float*)d_in[2];  // (200,16,20400) one-hot
    const float* W       = (const float*)d_in[3];  // (20000,512)
    // d_in[4] = b (20000): cancels in softmax over batch -> unused
    const float* Wc      = (const float*)d_in[5];  // (1,512)
    const float* bc      = (const float*)d_in[6];  // (1,)
    float* out   = (float*)d_out;                  // (50,16,20400)
    int* src_ids = (int*)d_ws;                     // 3200 ints

    fused_main<<<dim3(GEMM_BLOCKS + ZERO_BLOCKS + SCAN_BLOCKS), dim3(NTHREADS), 0, stream>>>(
        hidden, src_map, W, Wc, bc, out, src_ids);
    scatter_copy<<<dim3(TLEN * BATCH), dim3(64), 0, stream>>>(
        hidden, attn, Wc, bc, src_ids, out);
}